// Round 6
// baseline (27088.028 us; speedup 1.0000x reference)
//
#include <hip/hip_runtime.h>
#include <hip/hip_bf16.h>

typedef __bf16 bf16;
typedef __bf16 bf16x8 __attribute__((ext_vector_type(8)));
typedef float  f32x4  __attribute__((ext_vector_type(4)));

#define MFMA16(a,b,c) __builtin_amdgcn_mfma_f32_16x16x32_bf16((a),(b),(c),0,0,0)
#define NSTEP 119
#define BM 16

// ws offsets (bf16 elements); frag block (c,kt) = 1024 bf16: [hi 512][lo 512]
#define O_Z2H   0u
#define O_WIH0  196608u
#define O_WHH0  294912u
#define O_WIH1  688128u
#define O_WHH1  1081344u
#define O_WIH2  1474560u
#define O_WHH2  1867776u
#define O_OUTW  2260992u

// A-fragment-major offset for element (row m, col k): lane = m+16*((k>>3)&3), elem k&7
#define FOFF(m,k) (((k)>>5)*512 + ((m) + 16*(((k)>>3)&3))*8 + ((k)&7))

__device__ __forceinline__ f32x4 splat4(float v){ f32x4 r={v,v,v,v}; return r; }

// fp32 W[Rt*16][KT*32] row-major -> MFMA B-fragments, hi/lo bf16 split.
__global__ void pack2(const float* __restrict__ src, bf16* __restrict__ dst,
                      int Rt, int KT) {
  int idx = blockIdx.x * 256 + threadIdx.x;
  if (idx >= Rt * KT * 64) return;
  int lane = idx & 63, fi = idx >> 6;
  int r15 = lane & 15, q = lane >> 4;
  int c = fi / KT, kt = fi - c * KT;
  const float* s = src + (size_t)(c * 16 + r15) * (KT * 32) + kt * 32 + q * 8;
  bf16* dhi = dst + (size_t)fi * 1024 + lane * 8;
  bf16* dlo = dhi + 512;
  #pragma unroll
  for (int e = 0; e < 8; ++e) {
    float v = s[e];
    bf16 hi = (bf16)v;
    dhi[e] = hi;
    dlo[e] = (bf16)(v - (float)hi);
  }
}

// acc[NT] += A x W^T, 3-pass split MFMA. A comps frag-major in LDS.
template<int KT, int NT>
__device__ __forceinline__ void gemm3f(f32x4* acc,
    const bf16* __restrict__ A0, const bf16* __restrict__ A1,
    const bf16* __restrict__ BF, const int cbase, const int cstep, const int lane)
{
  #pragma unroll
  for (int kt = 0; kt < KT; ++kt) {
    bf16x8 a0 = *(const bf16x8*)(A0 + kt * 512 + lane * 8);
    bf16x8 a1 = *(const bf16x8*)(A1 + kt * 512 + lane * 8);
    #pragma unroll
    for (int t = 0; t < NT; ++t) {
      const bf16* bp = BF + (size_t)((cbase + t * cstep) * KT + kt) * 1024 + lane * 8;
      bf16x8 b0 = *(const bf16x8*)bp;
      bf16x8 b1 = *(const bf16x8*)(bp + 512);
      acc[t] = MFMA16(a0, b0, acc[t]);
      acc[t] = MFMA16(a1, b0, acc[t]);
      acc[t] = MFMA16(a0, b1, acc[t]);
    }
  }
}

// GRU gate update for one layer; h comps 0/1 in LDS (frag-major), comp2 in regs.
__device__ __forceinline__ void upd(bf16* __restrict__ hc0, bf16* __restrict__ hc1,
    const f32x4 ai[3], const f32x4 ah[3], float c2[4], const int q, const int j)
{
  #pragma unroll
  for (int r = 0; r < 4; ++r) {
    const int m = q * 4 + r;
    const int off = FOFF(m, j);
    float rg = 1.f / (1.f + expf(-(ai[0][r] + ah[0][r])));
    float zg = 1.f / (1.f + expf(-(ai[1][r] + ah[1][r])));
    float ng = tanhf(ai[2][r] + rg * ah[2][r]);
    float hp = (float)hc0[off] + (float)hc1[off] + c2[r];
    float hv = (1.f - zg) * ng + zg * hp;
    bf16 d0 = (bf16)hv;  float r1 = hv - (float)d0;
    bf16 d1 = (bf16)r1;  c2[r] = r1 - (float)d1;
    hc0[off] = d0;
    hc1[off] = d1;
  }
}

__global__ __launch_bounds__(1024, 4)
void moldec_mfma(const float* __restrict__ z, const float* __restrict__ emb,
                 const float* __restrict__ z2h_b, const float* __restrict__ out_b,
                 const float* __restrict__ bih0, const float* __restrict__ bhh0,
                 const float* __restrict__ bih1, const float* __restrict__ bhh1,
                 const float* __restrict__ bih2, const float* __restrict__ bhh2,
                 const bf16* __restrict__ wsb, float* __restrict__ out)
{
  __shared__ __align__(16) bf16 hS[3][2][4096];   // [layer][comp][kt*512] frag-major
  __shared__ __align__(16) bf16 xzS[2][4][512];   // x (kt 0-1) / z-init (kt 0-3)
  __shared__ float logS2[2][16][66];
  __shared__ bf16 pad_[8192];                     // LDS>80KB: force 1 block/CU

  const int tid  = threadIdx.x;
  const int wave = tid >> 6;
  const int lane = tid & 63;
  const int q    = lane >> 4;
  const int r15  = lane & 15;
  const int b0   = blockIdx.x * BM;
  const int j0   = wave * 16;
  const int j    = j0 + r15;       // neuron owned by this thread (per layer)
  if (out == nullptr) pad_[0] = (bf16)0.f;   // keep pad_ alive

  // hoisted per-thread biases [layer][gate] at col j
  float bi_[3][3], bh_[3][3];
  #pragma unroll
  for (int g = 0; g < 3; ++g) {
    bi_[0][g] = bih0[g * 256 + j];  bh_[0][g] = bhh0[g * 256 + j];
    bi_[1][g] = bih1[g * 256 + j];  bh_[1][g] = bhh1[g * 256 + j];
    bi_[2][g] = bih2[g * 256 + j];  bh_[2][g] = bhh2[g * 256 + j];
  }
  float c2_0[4], c2_1[4], c2_2[4];   // h comp2 per layer, rows m=q*4+r

  // ---- stage z into frag layout (2 comps) ----
  if (tid < 512) {
    const int m = tid >> 5, c4 = (tid & 31) * 4;
    float4 v = *(const float4*)(z + (size_t)(b0 + m) * 128 + c4);
    const float vv[4] = {v.x, v.y, v.z, v.w};
    #pragma unroll
    for (int e = 0; e < 4; ++e) {
      const int off = FOFF(m, c4 + e);
      bf16 hi = (bf16)vv[e];
      (&xzS[0][0][0])[off] = hi;
      (&xzS[1][0][0])[off] = (bf16)(vv[e] - (float)hi);
    }
  }
  __syncthreads();

  // ---- h0 = tanh(z @ z2h_w.T + b); wave w owns neuron j of all 3 layers ----
  {
    f32x4 acc[3];
    #pragma unroll
    for (int t = 0; t < 3; ++t) acc[t] = splat4(z2h_b[t * 256 + j]);
    gemm3f<4, 3>(acc, &xzS[0][0][0], &xzS[1][0][0], wsb + O_Z2H, wave, 16, lane);
    #pragma unroll
    for (int t = 0; t < 3; ++t) {
      float* c2p = t == 0 ? c2_0 : (t == 1 ? c2_1 : c2_2);
      #pragma unroll
      for (int r = 0; r < 4; ++r) {
        const int m = q * 4 + r;
        const int off = FOFF(m, j);
        float hv = tanhf(acc[t][r]);
        bf16 d0 = (bf16)hv;  float r1 = hv - (float)d0;
        bf16 d1 = (bf16)r1;  c2p[r] = r1 - (float)d1;
        hS[t][0][off] = d0;
        hS[t][1][off] = d1;
      }
    }
  }
  __syncthreads();

  // ---- stage x = emb[1] (wave w = batch row w, lane = elem) ----
  {
    float ev = emb[64 + lane];
    const int off = FOFF(wave, lane);
    bf16 hi = (bf16)ev;
    (&xzS[0][0][0])[off] = hi;
    (&xzS[1][0][0])[off] = (bf16)(ev - (float)hi);
  }
  __syncthreads();

  for (int step = 0; step < NSTEP; ++step) {
    // ---- B: grand GEMM phase (all reads are pre-step state) ----
    f32x4 ai0[3], ah0[3], ah1[3], ah2[3];
    #pragma unroll
    for (int t = 0; t < 3; ++t) {
      ai0[t] = splat4(bi_[0][t]);
      ah0[t] = splat4(bh_[0][t]);
      ah1[t] = splat4(bh_[1][t]);
      ah2[t] = splat4(bh_[2][t]);
    }
    gemm3f<2, 3>(ai0, &xzS[0][0][0], &xzS[1][0][0], wsb + O_WIH0, wave, 16, lane);
    gemm3f<8, 3>(ah0, hS[0][0], hS[0][1], wsb + O_WHH0, wave, 16, lane);
    gemm3f<8, 3>(ah1, hS[1][0], hS[1][1], wsb + O_WHH1, wave, 16, lane);
    gemm3f<8, 3>(ah2, hS[2][0], hS[2][1], wsb + O_WHH2, wave, 16, lane);
    __syncthreads();

    // ---- C: update h0 ----
    upd(hS[0][0], hS[0][1], ai0, ah0, c2_0, q, j);
    __syncthreads();

    // ---- D+E: ai1 = wih1 @ h0'; update h1 (no sync between: disjoint arrays) ----
    {
      f32x4 ai1[3];
      #pragma unroll
      for (int t = 0; t < 3; ++t) ai1[t] = splat4(bi_[1][t]);
      gemm3f<8, 3>(ai1, hS[0][0], hS[0][1], wsb + O_WIH1, wave, 16, lane);
      upd(hS[1][0], hS[1][1], ai1, ah1, c2_1, q, j);
    }
    __syncthreads();

    // ---- F+G: ai2 = wih2 @ h1'; update h2 ----
    {
      f32x4 ai2[3];
      #pragma unroll
      for (int t = 0; t < 3; ++t) ai2[t] = splat4(bi_[2][t]);
      gemm3f<8, 3>(ai2, hS[1][0], hS[1][1], wsb + O_WIH2, wave, 16, lane);
      upd(hS[2][0], hS[2][1], ai2, ah2, c2_2, q, j);
    }
    __syncthreads();

    // ---- H: logits partials; wave = (col-tile tt, K-half kh) ----
    if (wave < 8) {
      const int tt = wave >> 1, kh = wave & 1;
      f32x4 acc = (kh == 0) ? splat4(out_b[tt * 16 + r15]) : splat4(0.f);
      gemm3f<4, 1>(&acc, hS[2][0] + kh * 2048, hS[2][1] + kh * 2048,
                   wsb + O_OUTW + (size_t)(tt * 8 + kh * 4) * 1024, 0, 0, lane);
      #pragma unroll
      for (int r = 0; r < 4; ++r)
        logS2[kh][q * 4 + r][tt * 16 + r15] = acc[r];
    }
    __syncthreads();

    // ---- I: per-row store + argmax + next-x stage (wave w = row w) ----
    {
      float v = logS2[0][wave][lane] + logS2[1][wave][lane];
      __builtin_nontemporal_store(v, out + ((size_t)(b0 + wave) * NSTEP + step) * 64 + lane);
      float bv = v;
      int   bi = lane;
      #pragma unroll
      for (int d = 1; d < 64; d <<= 1) {
        float ov = __shfl_xor(bv, d);
        int   oi = __shfl_xor(bi, d);
        if (ov > bv || (ov == bv && oi < bi)) { bv = ov; bi = oi; }
      }
      float ev = emb[(size_t)bi * 64 + lane];
      const int off = FOFF(wave, lane);
      bf16 hi = (bf16)ev;
      (&xzS[0][0][0])[off] = hi;
      (&xzS[1][0][0])[off] = (bf16)(ev - (float)hi);
    }
    __syncthreads();
  }
}

extern "C" void kernel_launch(void* const* d_in, const int* in_sizes, int n_in,
                              void* d_out, int out_size, void* d_ws, size_t ws_size,
                              hipStream_t stream) {
  bf16* wsb = (bf16*)d_ws;

  pack2<<<48, 256, 0, stream>>>((const float*)d_in[2],  wsb + O_Z2H,  48, 4);
  pack2<<<24, 256, 0, stream>>>((const float*)d_in[6],  wsb + O_WIH0, 48, 2);
  pack2<<<96, 256, 0, stream>>>((const float*)d_in[7],  wsb + O_WHH0, 48, 8);
  pack2<<<96, 256, 0, stream>>>((const float*)d_in[10], wsb + O_WIH1, 48, 8);
  pack2<<<96, 256, 0, stream>>>((const float*)d_in[11], wsb + O_WHH1, 48, 8);
  pack2<<<96, 256, 0, stream>>>((const float*)d_in[14], wsb + O_WIH2, 48, 8);
  pack2<<<96, 256, 0, stream>>>((const float*)d_in[15], wsb + O_WHH2, 48, 8);
  pack2<<<8,  256, 0, stream>>>((const float*)d_in[4],  wsb + O_OUTW, 4,  8);

  moldec_mfma<<<256, 1024, 0, stream>>>(
      (const float*)d_in[0],  (const float*)d_in[1],
      (const float*)d_in[3],  (const float*)d_in[5],
      (const float*)d_in[8],  (const float*)d_in[9],
      (const float*)d_in[12], (const float*)d_in[13],
      (const float*)d_in[16], (const float*)d_in[17],
      wsb, (float*)d_out);
}